// Round 1
// baseline (642.754 us; speedup 1.0000x reference)
//
#include <hip/hip_runtime.h>
#include <math.h>

#define N_INST 512
#define LSEQ 512
#define EMB 128
#define NF 128
#define KW 3
#define HID 384
#define ATT 128
#define NCLS 53

#define XCOLS 69   // tile columns: global cols c0-4 .. c0+64
#define XSTRIDE 72 // padded LDS row stride (16B aligned, breaks pow2 conflicts)
#define LC 64      // output columns per chunk

// ---------------- prep: weight transposes ----------------
__global__ __launch_bounds__(256) void prep_kernel(const float* __restrict__ conv_w,
                                                   const float* __restrict__ W_w,
                                                   float* __restrict__ wt,
                                                   float* __restrict__ wwt) {
  int i = blockIdx.x * 256 + threadIdx.x;
  if (i < NF * EMB * KW) {
    int f = i / (EMB * KW);
    int r = i % (EMB * KW);
    int e = r / KW;
    int k = r % KW;
    wt[e * (KW * NF) + k * NF + f] = conv_w[i];  // wt[e][k][f]
  }
  if (i < ATT * HID) {
    int a = i / HID;
    int h = i % HID;
    wwt[h * ATT + a] = W_w[i];  // wwt[h][a]
  }
}

// ---------------- fused embed + conv + relu + piecewise max + attn score ----------------
__global__ __launch_bounds__(256) void pcnn_kernel(
    const int* __restrict__ char_ids, const int* __restrict__ pos_e1,
    const int* __restrict__ pos_e2, const float* __restrict__ emb,
    const float* __restrict__ conv_b, const float* __restrict__ wt,
    const float* __restrict__ wwt, const float* __restrict__ W_b,
    const float* __restrict__ u_w, float* __restrict__ Hout,
    float* __restrict__ scores) {
  __shared__ float xs[EMB][XSTRIDE];  // 36 KB embedded-x tile
  __shared__ float red[256][4];
  __shared__ float Hrow[HID];
  __shared__ float red2[128];

  const int n = blockIdx.x;
  const int t = threadIdx.x;
  const int f = t & 127;   // filter = lane-ish -> coalesced weight loads
  const int cg = t >> 7;   // column group: 0 -> cols 0..31, 1 -> 32..63 of chunk

  // per-row segment boundaries (mirrors reference exactly)
  int p1 = pos_e1[n], p2 = pos_e2[n];
  int e1v = min(p1, p2), e2v = max(p1, p2);
  e1v = min(max(e1v, 0), LSEQ);
  e2v = min(max(e2v, 0), LSEQ);
  if (e1v == e2v) e2v = min(e1v + 1, LSEQ);
  const int end1 = (e1v > 0) ? e1v : 1;

  const float bf = conv_b[f];
  float max1 = -3.402823466e38f, max2 = -3.402823466e38f, max3 = -3.402823466e38f;

  const int le = t & 127;  // e index for tile loads (coalesced over emb row)
  const int j0 = t >> 7;   // starting column for tile loads

  for (int c = 0; c < LSEQ / LC; ++c) {
    const int c0 = c * LC;
    __syncthreads();
    // stage x tile: xs[e][j] = emb[char_ids[n, c0-4+j]][e], 0 outside [0,L)
    for (int j = j0; j < XCOLS; j += 2) {
      int g = c0 - 4 + j;
      float v = 0.0f;
      if (g >= 0 && g < LSEQ) {
        int cid = char_ids[n * LSEQ + g];
        v = emb[cid * EMB + le];
      }
      xs[le][j] = v;
    }
    __syncthreads();

    float acc[32];
#pragma unroll
    for (int jj = 0; jj < 32; ++jj) acc[jj] = 0.0f;

    const float* wtf = wt + f;
    for (int e = 0; e < EMB; ++e) {
      // 10 aligned float4 LDS reads (same-address broadcast within wave)
      float xf[40];
      const float* xrow = &xs[e][cg << 5];
#pragma unroll
      for (int q = 0; q < 10; ++q) {
        float4 v = *(const float4*)(xrow + 4 * q);
        xf[4 * q + 0] = v.x;
        xf[4 * q + 1] = v.y;
        xf[4 * q + 2] = v.z;
        xf[4 * q + 3] = v.w;
      }
      const float w0 = wtf[e * 384 + 0];
      const float w1 = wtf[e * 384 + 128];
      const float w2 = wtf[e * 384 + 256];
      // output col l = c0 + cg*32 + jj needs x cols l-1,l,l+1 -> xf[jj+3..jj+5]
#pragma unroll
      for (int jj = 0; jj < 32; ++jj) {
        acc[jj] = fmaf(w0, xf[jj + 3],
                  fmaf(w1, xf[jj + 4],
                  fmaf(w2, xf[jj + 5], acc[jj])));
      }
    }

    // relu + 3-segment running max
#pragma unroll
    for (int jj = 0; jj < 32; ++jj) {
      float y = fmaxf(acc[jj] + bf, 0.0f);
      int l = c0 + (cg << 5) + jj;
      if (l < end1) max1 = fmaxf(max1, y);
      if (l >= e1v && l < e2v) max2 = fmaxf(max2, y);
      bool in3 = (e2v < LSEQ) ? (l >= e2v) : (l == LSEQ - 1);
      if (in3) max3 = fmaxf(max3, y);
    }
  }

  // combine the two column groups
  __syncthreads();
  red[t][0] = max1; red[t][1] = max2; red[t][2] = max3;
  __syncthreads();
  if (t < 128) {
    float h0 = fmaxf(red[t][0], red[t + 128][0]);
    float h1 = fmaxf(red[t][1], red[t + 128][1]);
    float h2 = fmaxf(red[t][2], red[t + 128][2]);
    Hrow[0 * NF + f] = h0;
    Hrow[1 * NF + f] = h1;
    Hrow[2 * NF + f] = h2;
    Hout[n * HID + 0 * NF + f] = h0;
    Hout[n * HID + 1 * NF + f] = h1;
    Hout[n * HID + 2 * NF + f] = h2;
  }
  __syncthreads();

  // attention score for this instance: tanh(H . W^T + b) . u
  float val = 0.0f;
  if (t < ATT) {
    float s = W_b[t];
#pragma unroll 8
    for (int h = 0; h < HID; ++h) s = fmaf(Hrow[h], wwt[h * ATT + t], s);
    val = tanhf(s) * u_w[t];
  }
  if (t < 128) red2[t] = val;
  __syncthreads();
  for (int off = 64; off > 0; off >>= 1) {
    if (t < off) red2[t] += red2[t + off];
    __syncthreads();
  }
  if (t == 0) scores[n] = red2[0];
}

// ---------------- softmax over instances + bag aggregation + logits ----------------
__global__ __launch_bounds__(256) void finalize_kernel(
    const float* __restrict__ scores, const float* __restrict__ H,
    const float* __restrict__ fc_w, const float* __restrict__ fc_b,
    float* __restrict__ out) {
  __shared__ float sattn[N_INST];
  __shared__ float sred[256];
  __shared__ float hbag[HID];
  const int t = threadIdx.x;
  float s0 = scores[t];
  float s1 = scores[t + 256];
  sred[t] = fmaxf(s0, s1);
  __syncthreads();
  for (int off = 128; off > 0; off >>= 1) {
    if (t < off) sred[t] = fmaxf(sred[t], sred[t + off]);
    __syncthreads();
  }
  float mx = sred[0];
  __syncthreads();
  float ex0 = expf(s0 - mx), ex1 = expf(s1 - mx);
  sred[t] = ex0 + ex1;
  __syncthreads();
  for (int off = 128; off > 0; off >>= 1) {
    if (t < off) sred[t] += sred[t + off];
    __syncthreads();
  }
  float inv = 1.0f / sred[0];
  float a0 = ex0 * inv, a1 = ex1 * inv;
  sattn[t] = a0;
  sattn[t + 256] = a1;
  out[NCLS + t] = a0;
  out[NCLS + 256 + t] = a1;
  __syncthreads();

  for (int cc = t; cc < HID; cc += 256) {
    float acc = 0.0f;
    for (int n2 = 0; n2 < N_INST; ++n2) acc = fmaf(sattn[n2], H[n2 * HID + cc], acc);
    hbag[cc] = acc;
  }
  __syncthreads();
  if (t < NCLS) {
    float acc = fc_b[t];
    for (int h = 0; h < HID; ++h) acc = fmaf(hbag[h], fc_w[t * HID + h], acc);
    out[t] = acc;
  }
}

extern "C" void kernel_launch(void* const* d_in, const int* in_sizes, int n_in,
                              void* d_out, int out_size, void* d_ws, size_t ws_size,
                              hipStream_t stream) {
  const int* char_ids = (const int*)d_in[0];
  const int* pos_e1 = (const int*)d_in[1];
  const int* pos_e2 = (const int*)d_in[2];
  const float* emb = (const float*)d_in[3];
  const float* conv_w = (const float*)d_in[4];
  const float* conv_b = (const float*)d_in[5];
  const float* W_w = (const float*)d_in[6];
  const float* W_b = (const float*)d_in[7];
  const float* u_w = (const float*)d_in[8];
  const float* fc_w = (const float*)d_in[9];
  const float* fc_b = (const float*)d_in[10];
  float* out = (float*)d_out;
  float* ws = (float*)d_ws;

  float* wt = ws;                       // 49152 f
  float* wwt = wt + NF * EMB * KW;      // 49152 f
  float* H = wwt + ATT * HID;           // 196608 f
  float* scores = H + N_INST * HID;     // 512 f

  hipLaunchKernelGGL(prep_kernel, dim3(192), dim3(256), 0, stream, conv_w, W_w, wt, wwt);
  hipLaunchKernelGGL(pcnn_kernel, dim3(N_INST), dim3(256), 0, stream,
                     char_ids, pos_e1, pos_e2, emb, conv_b, wt, wwt, W_b, u_w, H, scores);
  hipLaunchKernelGGL(finalize_kernel, dim3(1), dim3(256), 0, stream, scores, H, fc_w, fc_b, out);
}

// Round 4
// 483.544 us; speedup vs baseline: 1.3293x; 1.3293x over previous
//
#include <hip/hip_runtime.h>
#include <math.h>
#include <float.h>

#define N_INST 512
#define LSEQ 512
#define EMB 128
#define NF 128
#define KW 3
#define HID 384
#define ATT 128
#define NCLS 53

#define XSTRIDE 67   // odd LDS stride (floats): all patterns <=2-way bank aliasing = free

// ---------------- zero H ----------------
__global__ __launch_bounds__(256) void zero_kernel(float* __restrict__ H) {
  int i = blockIdx.x * 256 + threadIdx.x;
  if (i < N_INST * HID) H[i] = 0.0f;
}

// ---------------- prep: weight transposes ----------------
__global__ __launch_bounds__(256) void prep_kernel(const float* __restrict__ conv_w,
                                                   const float* __restrict__ W_w,
                                                   float* __restrict__ wt,
                                                   float* __restrict__ wwt) {
  int i = blockIdx.x * 256 + threadIdx.x;
  if (i < NF * EMB * KW) {
    int f = i / (EMB * KW);
    int r = i % (EMB * KW);
    int e = r / KW;
    int k = r % KW;
    wt[e * (KW * NF) + k * NF + f] = conv_w[i];  // wt[e][k][f]
  }
  if (i < ATT * HID) {
    int a = i / HID;
    int h = i % HID;
    wwt[h * ATT + a] = W_w[i];  // wwt[h][a]
  }
}

// ---------------- fused embed + conv + relu + piecewise max ----------------
// grid = N_INST * 8 (8 column-splits of 64 output cols each), block = 256.
// Thread tile: 8 filters x 8 columns; e-dim split across the two 128-thread
// halves (partial sums combined through LDS). Per e-step per lane:
// 10 ds_read_b32 + 6 global float4 (weights) feed 192 FMAs -> VALU-bound.
__global__ __launch_bounds__(256, 3) void pcnn_kernel(
    const int* __restrict__ char_ids, const int* __restrict__ pos_e1,
    const int* __restrict__ pos_e2, const float* __restrict__ emb,
    const float* __restrict__ conv_b, const float* __restrict__ wt,
    float* __restrict__ H) {
  __shared__ float xs[EMB * XSTRIDE];  // 34.3 KB; reused as scratch for reductions

  const int n = blockIdx.x >> 3;
  const int split = blockIdx.x & 7;
  const int c0 = split * 64;
  const int t = threadIdx.x;

  // ---- stage x tile: xs[e][j] = emb[char_ids[n, c0-1+j]][e], j in [0,66) ----
  {
    const int eL = t & 127;
    const int jh = t >> 7;
    for (int j = jh; j < 66; j += 2) {
      int g = c0 - 1 + j;
      float v = 0.0f;
      if ((unsigned)g < (unsigned)LSEQ) {
        int cid = char_ids[n * LSEQ + g];
        v = emb[cid * EMB + eL];
      }
      xs[eL * XSTRIDE + j] = v;  // bank = (3e+j)%32 over lanes: 2-way, free
    }
  }
  __syncthreads();

  // ---- compute: each thread 8 filters x 8 cols, over its 64-e half ----
  const int half = t >> 7;       // e in [half*64, half*64+64)
  const int tt = t & 127;
  const int cgl = tt & 7;        // column group: cols c0 + 8*cgl .. +7
  const int fg = tt >> 3;        // filter group: f = 8*fg .. +7

  float acc[8][8];
#pragma unroll
  for (int i = 0; i < 8; ++i)
#pragma unroll
    for (int u = 0; u < 8; ++u) acc[i][u] = 0.0f;

  const float* xb = xs + (half * 64) * XSTRIDE + cgl * 8;
  const float* wb = wt + (half * 64) * (KW * NF) + fg * 8;

#pragma unroll 2
  for (int e = 0; e < 64; ++e) {
    float xf[10];
#pragma unroll
    for (int d = 0; d < 10; ++d) xf[d] = xb[e * XSTRIDE + d];
    float w[3][8];
#pragma unroll
    for (int k = 0; k < 3; ++k) {
      float4 a = *(const float4*)(wb + e * (KW * NF) + k * NF);
      float4 b = *(const float4*)(wb + e * (KW * NF) + k * NF + 4);
      w[k][0] = a.x; w[k][1] = a.y; w[k][2] = a.z; w[k][3] = a.w;
      w[k][4] = b.x; w[k][5] = b.y; w[k][6] = b.z; w[k][7] = b.w;
    }
#pragma unroll
    for (int k = 0; k < 3; ++k)
#pragma unroll
      for (int i = 0; i < 8; ++i)
#pragma unroll
        for (int u = 0; u < 8; ++u)
          acc[i][u] = fmaf(w[k][i], xf[u + k], acc[i][u]);
  }

  __syncthreads();

  // ---- combine e-halves through LDS: half0 writes, half1 adds ----
  float* scr = xs;  // reuse: scr[f][cc], 128*64 floats = 32 KB
  if (half == 0) {
#pragma unroll
    for (int i = 0; i < 8; ++i)
#pragma unroll
      for (int u = 0; u < 8; ++u)
        scr[(fg * 8 + i) * 64 + cgl * 8 + u] = acc[i][u];
  }
  __syncthreads();

  // per-row segment boundaries (mirrors reference)
  int p1 = pos_e1[n], p2 = pos_e2[n];
  int e1v = min(p1, p2), e2v = max(p1, p2);
  e1v = min(max(e1v, 0), LSEQ);
  e2v = min(max(e2v, 0), LSEQ);
  if (e1v == e2v) e2v = min(e1v + 1, LSEQ);
  const int end1 = (e1v > 0) ? e1v : 1;

  float pm[8][3];
  if (half == 1) {
#pragma unroll
    for (int i = 0; i < 8; ++i) {
      pm[i][0] = -FLT_MAX; pm[i][1] = -FLT_MAX; pm[i][2] = -FLT_MAX;
      const int f = fg * 8 + i;
      const float bf = conv_b[f];
#pragma unroll
      for (int u = 0; u < 8; ++u) {
        int l = c0 + cgl * 8 + u;
        float y = fmaxf(acc[i][u] + scr[f * 64 + cgl * 8 + u] + bf, 0.0f);
        if (l < end1) pm[i][0] = fmaxf(pm[i][0], y);
        if (l >= e1v && l < e2v) pm[i][1] = fmaxf(pm[i][1], y);
        bool in3 = (e2v < LSEQ) ? (l >= e2v) : (l == LSEQ - 1);
        if (in3) pm[i][2] = fmaxf(pm[i][2], y);
      }
    }
  }
  __syncthreads();

  // ---- reduce over the 8 col-groups, then atomic-max into H ----
  if (half == 1) {
#pragma unroll
    for (int i = 0; i < 8; ++i)
#pragma unroll
      for (int s = 0; s < 3; ++s)
        xs[(fg * 8 + i) * 24 + s * 8 + cgl] = pm[i][s];
  }
  __syncthreads();
  if (t < 128) {
#pragma unroll
    for (int s = 0; s < 3; ++s) {
      float m = xs[t * 24 + s * 8 + 0];
#pragma unroll
      for (int c = 1; c < 8; ++c) m = fmaxf(m, xs[t * 24 + s * 8 + c]);
      // all relu'd values are >= 0; H is zero-initialized, so int-punned
      // atomicMax is order-preserving (non-negative IEEE floats).
      if (m >= 0.0f)
        atomicMax((int*)&H[n * HID + s * NF + t], __float_as_int(m));
    }
  }
}

// ---------------- attention score per instance ----------------
__global__ __launch_bounds__(128) void score_kernel(
    const float* __restrict__ H, const float* __restrict__ wwt,
    const float* __restrict__ W_b, const float* __restrict__ u_w,
    float* __restrict__ scores) {
  __shared__ float Hrow[HID];
  __shared__ float red2[128];
  const int n = blockIdx.x;
  const int t = threadIdx.x;
#pragma unroll
  for (int s = 0; s < 3; ++s) Hrow[s * NF + t] = H[n * HID + s * NF + t];
  __syncthreads();
  float ss = W_b[t];
#pragma unroll 8
  for (int h = 0; h < HID; ++h) ss = fmaf(Hrow[h], wwt[h * ATT + t], ss);
  red2[t] = tanhf(ss) * u_w[t];
  __syncthreads();
  for (int off = 64; off > 0; off >>= 1) {
    if (t < off) red2[t] += red2[t + off];
    __syncthreads();
  }
  if (t == 0) scores[n] = red2[0];
}

// ---------------- softmax over instances + bag aggregation + logits ----------------
__global__ __launch_bounds__(256) void finalize_kernel(
    const float* __restrict__ scores, const float* __restrict__ H,
    const float* __restrict__ fc_w, const float* __restrict__ fc_b,
    float* __restrict__ out) {
  __shared__ float sattn[N_INST];
  __shared__ float sred[256];
  __shared__ float hbag[HID];
  const int t = threadIdx.x;
  float s0 = scores[t];
  float s1 = scores[t + 256];
  sred[t] = fmaxf(s0, s1);
  __syncthreads();
  for (int off = 128; off > 0; off >>= 1) {
    if (t < off) sred[t] = fmaxf(sred[t], sred[t + off]);
    __syncthreads();
  }
  float mx = sred[0];
  __syncthreads();
  float ex0 = expf(s0 - mx), ex1 = expf(s1 - mx);
  sred[t] = ex0 + ex1;
  __syncthreads();
  for (int off = 128; off > 0; off >>= 1) {
    if (t < off) sred[t] += sred[t + off];
    __syncthreads();
  }
  float inv = 1.0f / sred[0];
  float a0 = ex0 * inv, a1 = ex1 * inv;
  sattn[t] = a0;
  sattn[t + 256] = a1;
  out[NCLS + t] = a0;
  out[NCLS + 256 + t] = a1;
  __syncthreads();

  for (int cc = t; cc < HID; cc += 256) {
    float acc = 0.0f;
    for (int n2 = 0; n2 < N_INST; ++n2) acc = fmaf(sattn[n2], H[n2 * HID + cc], acc);
    hbag[cc] = acc;
  }
  __syncthreads();
  if (t < NCLS) {
    float acc = fc_b[t];
    for (int h = 0; h < HID; ++h) acc = fmaf(hbag[h], fc_w[t * HID + h], acc);
    out[t] = acc;
  }
}

extern "C" void kernel_launch(void* const* d_in, const int* in_sizes, int n_in,
                              void* d_out, int out_size, void* d_ws, size_t ws_size,
                              hipStream_t stream) {
  const int* char_ids = (const int*)d_in[0];
  const int* pos_e1 = (const int*)d_in[1];
  const int* pos_e2 = (const int*)d_in[2];
  const float* emb = (const float*)d_in[3];
  const float* conv_w = (const float*)d_in[4];
  const float* conv_b = (const float*)d_in[5];
  const float* W_w = (const float*)d_in[6];
  const float* W_b = (const float*)d_in[7];
  const float* u_w = (const float*)d_in[8];
  const float* fc_w = (const float*)d_in[9];
  const float* fc_b = (const float*)d_in[10];
  float* out = (float*)d_out;
  float* ws = (float*)d_ws;

  float* wt = ws;                    // 49152 f
  float* wwt = wt + NF * EMB * KW;   // 49152 f
  float* H = wwt + ATT * HID;        // 196608 f
  float* scores = H + N_INST * HID;  // 512 f

  hipLaunchKernelGGL(zero_kernel, dim3((N_INST * HID + 255) / 256), dim3(256), 0, stream, H);
  hipLaunchKernelGGL(prep_kernel, dim3(192), dim3(256), 0, stream, conv_w, W_w, wt, wwt);
  hipLaunchKernelGGL(pcnn_kernel, dim3(N_INST * 8), dim3(256), 0, stream,
                     char_ids, pos_e1, pos_e2, emb, conv_b, wt, H);
  hipLaunchKernelGGL(score_kernel, dim3(N_INST), dim3(128), 0, stream, H, wwt, W_b, u_w, scores);
  hipLaunchKernelGGL(finalize_kernel, dim3(1), dim3(256), 0, stream, scores, H, fc_w, fc_b, out);
}

// Round 5
// 241.371 us; speedup vs baseline: 2.6629x; 2.0033x over previous
//
#include <hip/hip_runtime.h>
#include <hip/hip_bf16.h>
#include <math.h>
#include <float.h>

#define N_INST 512
#define LSEQ 512
#define EMB 128
#define NF 128
#define KW 3
#define HID 384
#define ATT 128
#define NCLS 53

#define XCOLS 66        // halo columns staged per block: c0-1 .. c0+64
#define XCOL_STRIDE 136 // ushorts per column (128 e + 8 pad) = 272 B, 16B-aligned

typedef __attribute__((ext_vector_type(8))) short short8;
typedef __attribute__((ext_vector_type(4))) float f32x4;

// ---------------- zero H ----------------
__global__ __launch_bounds__(256) void zero_kernel(float* __restrict__ H) {
  int i = blockIdx.x * 256 + threadIdx.x;
  if (i < N_INST * HID) H[i] = 0.0f;
}

// ---------------- prep: split W into bf16 hi/lo, fragment-major; transpose W_w ----------------
// Fragment layout: idx = (((kk*4 + eb)*8 + mf)*64 + L)*8 + i
//   A-frag (16x32): lane L supplies A[m = L&15][k = (L>>4)*8 + i]
//   f = mf*16 + (L&15), e = eb*32 + (L>>4)*8 + i
__global__ __launch_bounds__(256) void prep_kernel(const float* __restrict__ conv_w,
                                                   const float* __restrict__ W_w,
                                                   ushort* __restrict__ whi,
                                                   ushort* __restrict__ wlo,
                                                   float* __restrict__ wwt) {
  int i = blockIdx.x * 256 + threadIdx.x;  // 0 .. 49151 exactly
  {
    int ii = i & 7;
    int L  = (i >> 3) & 63;
    int mf = (i >> 9) & 7;
    int eb = (i >> 12) & 3;
    int kk = (i >> 14);  // 0..2
    int f = mf * 16 + (L & 15);
    int e = eb * 32 + (L >> 4) * 8 + ii;
    float v = conv_w[(f * EMB + e) * KW + kk];
    __hip_bfloat16 hb = __float2bfloat16(v);
    float hf = __bfloat162float(hb);
    __hip_bfloat16 lb = __float2bfloat16(v - hf);
    whi[i] = *reinterpret_cast<ushort*>(&hb);
    wlo[i] = *reinterpret_cast<ushort*>(&lb);
  }
  {
    int a = i / HID;
    int h = i % HID;
    wwt[h * ATT + a] = W_w[i];  // wwt[h][a]
  }
}

// ---------------- fused embed + conv(MFMA) + relu + piecewise max ----------------
// grid = N_INST*8 (64 output cols per block), 256 threads = 4 waves.
// Wave wv computes filters [wv*32, wv*32+32) x all 64 cols.
// K-loop: eb(4 e-blocks of 32) x kk(3 taps) x 3 split terms; no barriers inside.
__global__ __launch_bounds__(256) void pcnn_kernel(
    const int* __restrict__ char_ids, const int* __restrict__ pos_e1,
    const int* __restrict__ pos_e2, const float* __restrict__ emb,
    const float* __restrict__ conv_b, const ushort* __restrict__ whi,
    const ushort* __restrict__ wlo, float* __restrict__ H) {
  __shared__ ushort xh[XCOLS * XCOL_STRIDE];  // 17.95 KB
  __shared__ ushort xl[XCOLS * XCOL_STRIDE];  // 17.95 KB

  const int n = blockIdx.x >> 3;
  const int c0 = (blockIdx.x & 7) * 64;
  const int t = threadIdx.x;

  // ---- stage: gather emb rows, split fp32 -> bf16 hi+lo, column-major LDS ----
  {
    const int q = t & 3;  // e-quarter: e in [32q, 32q+32)
    for (int j = (t >> 2); j < XCOLS; j += 64) {
      int g = c0 - 1 + j;
      ushort* dh = xh + j * XCOL_STRIDE + q * 32;
      ushort* dl = xl + j * XCOL_STRIDE + q * 32;
      if ((unsigned)g < (unsigned)LSEQ) {
        int cid = char_ids[n * LSEQ + g];
        const float* er = emb + cid * EMB + q * 32;
#pragma unroll
        for (int c = 0; c < 4; ++c) {
          float4 v0 = *(const float4*)(er + c * 8);
          float4 v1 = *(const float4*)(er + c * 8 + 4);
          float vv[8] = {v0.x, v0.y, v0.z, v0.w, v1.x, v1.y, v1.z, v1.w};
          short8 hvec, lvec;
#pragma unroll
          for (int w = 0; w < 8; ++w) {
            __hip_bfloat16 hb = __float2bfloat16(vv[w]);
            float hf = __bfloat162float(hb);
            __hip_bfloat16 lb = __float2bfloat16(vv[w] - hf);
            hvec[w] = (short)*reinterpret_cast<ushort*>(&hb);
            lvec[w] = (short)*reinterpret_cast<ushort*>(&lb);
          }
          *(short8*)(dh + c * 8) = hvec;
          *(short8*)(dl + c * 8) = lvec;
        }
      } else {
        short8 z = {0, 0, 0, 0, 0, 0, 0, 0};
#pragma unroll
        for (int c = 0; c < 4; ++c) {
          *(short8*)(dh + c * 8) = z;
          *(short8*)(dl + c * 8) = z;
        }
      }
    }
  }
  __syncthreads();

  const int wv = t >> 6;   // wave id: f base = wv*32
  const int L = t & 63;
  const int lc = L & 15;   // column-in-fragment
  const int lg = L >> 4;   // 4-lane-group id

  f32x4 acc[2][4];
  const f32x4 zz = {0.f, 0.f, 0.f, 0.f};
#pragma unroll
  for (int mf = 0; mf < 2; ++mf)
#pragma unroll
    for (int nf = 0; nf < 4; ++nf) acc[mf][nf] = zz;

  for (int eb = 0; eb < 4; ++eb) {
#pragma unroll
    for (int kk = 0; kk < 3; ++kk) {
      short8 ah[2], al[2];
#pragma unroll
      for (int mf = 0; mf < 2; ++mf) {
        int fragi = ((kk * 4 + eb) * 8 + (wv * 2 + mf)) * 64 + L;
        ah[mf] = *(const short8*)(whi + fragi * 8);
        al[mf] = *(const short8*)(wlo + fragi * 8);
      }
#pragma unroll
      for (int nf = 0; nf < 4; ++nf) {
        // output col l = c0 + nf*16 + lc needs x col l+kk-1 -> halo idx nf*16+kk+lc
        int off = (nf * 16 + kk + lc) * XCOL_STRIDE + eb * 32 + lg * 8;
        short8 bh = *(const short8*)(xh + off);
        short8 bl = *(const short8*)(xl + off);
#pragma unroll
        for (int mf = 0; mf < 2; ++mf) {
          acc[mf][nf] = __builtin_amdgcn_mfma_f32_16x16x32_bf16(ah[mf], bh, acc[mf][nf], 0, 0, 0);
          acc[mf][nf] = __builtin_amdgcn_mfma_f32_16x16x32_bf16(ah[mf], bl, acc[mf][nf], 0, 0, 0);
          acc[mf][nf] = __builtin_amdgcn_mfma_f32_16x16x32_bf16(al[mf], bh, acc[mf][nf], 0, 0, 0);
        }
      }
    }
  }

  // ---- epilogue: bias + relu + segment maxes (D frag: row=(L>>4)*4+r, col=L&15) ----
  int p1 = pos_e1[n], p2 = pos_e2[n];
  int e1v = min(p1, p2), e2v = max(p1, p2);
  e1v = min(max(e1v, 0), LSEQ);
  e2v = min(max(e2v, 0), LSEQ);
  if (e1v == e2v) e2v = min(e1v + 1, LSEQ);
  const int end1 = (e1v > 0) ? e1v : 1;

#pragma unroll
  for (int mf = 0; mf < 2; ++mf) {
#pragma unroll
    for (int r = 0; r < 4; ++r) {
      int f = wv * 32 + mf * 16 + lg * 4 + r;
      float bias = conv_b[f];
      float m1 = -FLT_MAX, m2 = -FLT_MAX, m3 = -FLT_MAX;
#pragma unroll
      for (int nf = 0; nf < 4; ++nf) {
        int l = c0 + nf * 16 + lc;
        float y = fmaxf(acc[mf][nf][r] + bias, 0.0f);
        if (l < end1) m1 = fmaxf(m1, y);
        if (l >= e1v && l < e2v) m2 = fmaxf(m2, y);
        bool in3 = (e2v < LSEQ) ? (l >= e2v) : (l == LSEQ - 1);
        if (in3) m3 = fmaxf(m3, y);
      }
#pragma unroll
      for (int off = 1; off < 16; off <<= 1) {
        m1 = fmaxf(m1, __shfl_xor(m1, off, 64));
        m2 = fmaxf(m2, __shfl_xor(m2, off, 64));
        m3 = fmaxf(m3, __shfl_xor(m3, off, 64));
      }
      if (lc == 0) {
        // relu'd values >= 0; H zero-initialized -> int-punned atomicMax is exact
        if (m1 >= 0.0f) atomicMax((int*)&H[n * HID + 0 * NF + f], __float_as_int(m1));
        if (m2 >= 0.0f) atomicMax((int*)&H[n * HID + 1 * NF + f], __float_as_int(m2));
        if (m3 >= 0.0f) atomicMax((int*)&H[n * HID + 2 * NF + f], __float_as_int(m3));
      }
    }
  }
}

// ---------------- attention score per instance ----------------
__global__ __launch_bounds__(128) void score_kernel(
    const float* __restrict__ H, const float* __restrict__ wwt,
    const float* __restrict__ W_b, const float* __restrict__ u_w,
    float* __restrict__ scores) {
  __shared__ float Hrow[HID];
  __shared__ float red2[128];
  const int n = blockIdx.x;
  const int t = threadIdx.x;
#pragma unroll
  for (int s = 0; s < 3; ++s) Hrow[s * NF + t] = H[n * HID + s * NF + t];
  __syncthreads();
  float ss = W_b[t];
#pragma unroll 8
  for (int h = 0; h < HID; ++h) ss = fmaf(Hrow[h], wwt[h * ATT + t], ss);
  red2[t] = tanhf(ss) * u_w[t];
  __syncthreads();
  for (int off = 64; off > 0; off >>= 1) {
    if (t < off) red2[t] += red2[t + off];
    __syncthreads();
  }
  if (t == 0) scores[n] = red2[0];
}

// ---------------- softmax over instances + bag aggregation + logits ----------------
__global__ __launch_bounds__(256) void finalize_kernel(
    const float* __restrict__ scores, const float* __restrict__ H,
    const float* __restrict__ fc_w, const float* __restrict__ fc_b,
    float* __restrict__ out) {
  __shared__ float sattn[N_INST];
  __shared__ float sred[256];
  __shared__ float hbag[HID];
  const int t = threadIdx.x;
  float s0 = scores[t];
  float s1 = scores[t + 256];
  sred[t] = fmaxf(s0, s1);
  __syncthreads();
  for (int off = 128; off > 0; off >>= 1) {
    if (t < off) sred[t] = fmaxf(sred[t], sred[t + off]);
    __syncthreads();
  }
  float mx = sred[0];
  __syncthreads();
  float ex0 = expf(s0 - mx), ex1 = expf(s1 - mx);
  sred[t] = ex0 + ex1;
  __syncthreads();
  for (int off = 128; off > 0; off >>= 1) {
    if (t < off) sred[t] += sred[t + off];
    __syncthreads();
  }
  float inv = 1.0f / sred[0];
  float a0 = ex0 * inv, a1 = ex1 * inv;
  sattn[t] = a0;
  sattn[t + 256] = a1;
  out[NCLS + t] = a0;
  out[NCLS + 256 + t] = a1;
  __syncthreads();

  for (int cc = t; cc < HID; cc += 256) {
    float acc = 0.0f;
    for (int n2 = 0; n2 < N_INST; ++n2) acc = fmaf(sattn[n2], H[n2 * HID + cc], acc);
    hbag[cc] = acc;
  }
  __syncthreads();
  if (t < NCLS) {
    float acc = fc_b[t];
    for (int h = 0; h < HID; ++h) acc = fmaf(hbag[h], fc_w[t * HID + h], acc);
    out[t] = acc;
  }
}

extern "C" void kernel_launch(void* const* d_in, const int* in_sizes, int n_in,
                              void* d_out, int out_size, void* d_ws, size_t ws_size,
                              hipStream_t stream) {
  const int* char_ids = (const int*)d_in[0];
  const int* pos_e1 = (const int*)d_in[1];
  const int* pos_e2 = (const int*)d_in[2];
  const float* emb = (const float*)d_in[3];
  const float* conv_w = (const float*)d_in[4];
  const float* conv_b = (const float*)d_in[5];
  const float* W_w = (const float*)d_in[6];
  const float* W_b = (const float*)d_in[7];
  const float* u_w = (const float*)d_in[8];
  const float* fc_w = (const float*)d_in[9];
  const float* fc_b = (const float*)d_in[10];
  float* out = (float*)d_out;

  ushort* whi = (ushort*)d_ws;                     // 49152 ushorts
  ushort* wlo = whi + NF * EMB * KW;               // 49152 ushorts
  float* wwt = (float*)(wlo + NF * EMB * KW);      // 49152 floats (16B-aligned: 196608 B off)
  float* H = wwt + ATT * HID;                      // 196608 floats
  float* scores = H + N_INST * HID;                // 512 floats

  hipLaunchKernelGGL(zero_kernel, dim3((N_INST * HID + 255) / 256), dim3(256), 0, stream, H);
  hipLaunchKernelGGL(prep_kernel, dim3(192), dim3(256), 0, stream, conv_w, W_w, whi, wlo, wwt);
  hipLaunchKernelGGL(pcnn_kernel, dim3(N_INST * 8), dim3(256), 0, stream,
                     char_ids, pos_e1, pos_e2, emb, conv_b, whi, wlo, H);
  hipLaunchKernelGGL(score_kernel, dim3(N_INST), dim3(128), 0, stream, H, wwt, W_b, u_w, scores);
  hipLaunchKernelGGL(finalize_kernel, dim3(1), dim3(256), 0, stream, scores, H, fc_w, fc_b, out);
}